// Round 7
// baseline (1431.148 us; speedup 1.0000x reference)
//
#include <hip/hip_runtime.h>
#include <hip/hip_bf16.h>

// ---------------------------------------------------------------------------
// Hetero-GCN (3 node types, 9 relations), 2 GraphConv layers + classifier.
// Round 6:
//  - GEMM moved to matrix cores: 3-pass split-bf16 (A_hi*W_hi + A_hi*W_lo +
//    A_lo*W_hi), mfma_f32_16x16x32_bf16, fp32 accumulate. No LDS: A planes
//    row-major bf16 -> fragment = one 16B global load (L2-resident); W
//    pre-converted to chunk-major [4][128][32] bf16 planes by k_wprep.
//  - k_agg2 emits bf16 hi/lo planes directly (same write bytes as fp32).
//  - k_fill: NT store reverted (round-5: +63us, WRITE_SIZE up — NT defeats
//    L2 line-merging on random scatter).
// ---------------------------------------------------------------------------

#define NN 50000
#define EE 400000
#define NRG 2            // node ranges for histogram
#define RGN (NN / NRG)   // 25000 nodes per range
#define HCH 8            // edge chunks
#define HEG (EE / HCH)   // 50000 edges per chunk

typedef __attribute__((ext_vector_type(8))) short bf16x8;
typedef __attribute__((ext_vector_type(4))) float f32x4;
#define MFMA16(a, b, c) __builtin_amdgcn_mfma_f32_16x16x32_bf16(a, b, c, 0, 0, 0)

// ---------------- degree histogram (chunked, LDS, no global atomics) --------
__global__ __launch_bounds__(256) void k_hist(const int* __restrict__ edges,
                                              unsigned* __restrict__ hist) {
    __shared__ unsigned bins[RGN / 2];  // 12500 u32 = 50 KB
    int bid = blockIdx.x;
    int task = bid >> 4;           // r*2 + side
    int rem = bid & 15;
    int rg = rem >> 3;
    int c = rem & 7;
    int r = task >> 1, side = task & 1;
    int tid = threadIdx.x;
    for (int i = tid; i < RGN / 2; i += 256) bins[i] = 0;
    __syncthreads();
    const int* ea = edges + (size_t)r * 2 * EE + (size_t)side * EE + (size_t)c * HEG;
    int base = rg * RGN;
    for (int e = tid; e < HEG; e += 256) {
        int idx = __builtin_nontemporal_load(&ea[e]) - base;
        if ((unsigned)idx < (unsigned)RGN)
            atomicAdd(&bins[idx >> 1], (idx & 1) ? 65536u : 1u);
    }
    __syncthreads();
    unsigned* ho = hist + ((size_t)(task * NRG + rg) * HCH + c) * (RGN / 2);
    for (int i = tid; i < RGN / 2; i += 256) ho[i] = bins[i];
}

// ---------------- reduce histograms -> ns, nd, deg_d ------------------------
__global__ void k_sums(const unsigned* __restrict__ hist, float* __restrict__ ns,
                       float* __restrict__ nd, int* __restrict__ deg_d) {
    int i = blockIdx.x * blockDim.x + threadIdx.x;
    if (i >= 9 * (NN / 2)) return;
    int r = i / (NN / 2);
    int ps = i - r * (NN / 2);
    int rg = ps / (RGN / 2);
    int slot = ps - rg * (RGN / 2);
    const unsigned* hs = hist + ((size_t)((r * 2 + 0) * NRG + rg) * HCH) * (RGN / 2) + slot;
    const unsigned* hd = hist + ((size_t)((r * 2 + 1) * NRG + rg) * HCH) * (RGN / 2) + slot;
    unsigned slo = 0, shi = 0, dlo = 0, dhi = 0;
#pragma unroll
    for (int c = 0; c < HCH; ++c) {
        unsigned a = hs[(size_t)c * (RGN / 2)];
        unsigned b = hd[(size_t)c * (RGN / 2)];
        slo += a & 0xffffu; shi += a >> 16;
        dlo += b & 0xffffu; dhi += b >> 16;
    }
    int n0 = 2 * ps;
    ns[r * NN + n0]     = slo ? rsqrtf((float)slo) : 0.f;
    ns[r * NN + n0 + 1] = shi ? rsqrtf((float)shi) : 0.f;
    nd[r * NN + n0]     = dlo ? rsqrtf((float)dlo) : 0.f;
    nd[r * NN + n0 + 1] = dhi ? rsqrtf((float)dhi) : 0.f;
    deg_d[r * NN + n0]     = (int)dlo;
    deg_d[r * NN + n0 + 1] = (int)dhi;
}

// ---------------- exclusive scan of in-degrees -> CSR offsets ---------------
__global__ __launch_bounds__(256) void k_offsets(const int* __restrict__ deg_d,
                                                 int* __restrict__ off,
                                                 int* __restrict__ cur) {
    __shared__ int wsum[4];
    __shared__ int s_carry;
    int r = blockIdx.x;
    const int* c = deg_d + r * NN;
    int* o = off + r * (NN + 1);
    int* cu = cur + r * NN;
    int tid = threadIdx.x, lane = tid & 63, w = tid >> 6;
    if (tid == 0) s_carry = 0;
    __syncthreads();
    for (int base = 0; base < NN; base += 256) {
        int i = base + tid;
        int v = (i < NN) ? c[i] : 0;
        int x = v;
#pragma unroll
        for (int s = 1; s < 64; s <<= 1) {
            int y = __shfl_up(x, (unsigned)s);
            if (lane >= s) x += y;
        }
        if (lane == 63) wsum[w] = x;
        __syncthreads();
        int wbase = 0;
#pragma unroll
        for (int j = 0; j < 3; ++j) wbase += (j < w) ? wsum[j] : 0;
        int excl = s_carry + wbase + x - v;
        if (i < NN) { o[i] = excl; cu[i] = excl; }
        __syncthreads();
        if (tid == 255) s_carry += wbase + x;
    }
    __syncthreads();
    if (tid == 0) o[NN] = s_carry;
}

// ---------------- CSR fill (global atomics; plain store) --------------------
__global__ __launch_bounds__(256) void k_fill(const int* __restrict__ edges,
                                              int* __restrict__ cur,
                                              int* __restrict__ esrc) {
    int i = blockIdx.x * blockDim.x + threadIdx.x;
    if (i >= 9 * EE) return;
    int r = i / EE;
    int e = i - r * EE;
    int src = __builtin_nontemporal_load(&edges[(size_t)r * 2 * EE + e]);
    int dst = __builtin_nontemporal_load(&edges[(size_t)r * 2 * EE + EE + e]);
    int pos = atomicAdd(&cur[r * NN + dst], 1);
    esrc[(size_t)r * EE + pos] = src;
}

// ---------------- W prep: fp32 [K][N] -> chunk-major bf16 hi/lo planes ------
// out layout per (layer*9+r): [4 kchunks][128 n][32 k]
__global__ void k_wprep(const float* __restrict__ W1, const float* __restrict__ W2,
                        unsigned short* __restrict__ whi,
                        unsigned short* __restrict__ wlo) {
    int id = blockIdx.x * blockDim.x + threadIdx.x;
    const int total = 2 * 9 * 128 * 128;
    if (id >= total) return;
    int n = id & 127;
    int k = (id >> 7) & 127;
    int rl = id >> 14;  // layer*9 + r
    const float* W = (rl < 9) ? W1 : W2;
    int r = (rl < 9) ? rl : rl - 9;
    float f = W[((size_t)r * 128 + k) * 128 + n];
    unsigned u = __float_as_uint(f);
    unsigned hb = (u + 0x7fffu + ((u >> 16) & 1u)) & 0xffff0000u;
    float lo = f - __uint_as_float(hb);
    unsigned ul = __float_as_uint(lo);
    unsigned short l16 = (unsigned short)((ul + 0x7fffu + ((ul >> 16) & 1u)) >> 16);
    size_t oidx = (((size_t)rl * 4 + (k >> 5)) * 128 + n) * 32 + (k & 31);
    whi[oidx] = (unsigned short)(hb >> 16);
    wlo[oidx] = l16;
}

// ---------------- aggregation (CSR gather, one wave per dst row) ------------
// Emits bf16 hi/lo planes of the aggregated row.
struct AggT {
    const float* xin;
    const int* off;
    const int* esrc;
    const float* ns;
    const float* nd;
    unsigned short* Ah;
    unsigned short* Al;
};

template <int RELU>
__global__ __launch_bounds__(256) void k_agg2(AggT ta, AggT tb) {
    AggT t = (blockIdx.y == 0) ? ta : tb;
    int wave = (blockIdx.x * blockDim.x + threadIdx.x) >> 6;
    int lane = threadIdx.x & 63;
    if (wave >= NN) return;
    int e0 = t.off[wave], e1 = t.off[wave + 1];
    const float* xin = t.xin;
    const int* esrc = t.esrc;
    const float* ns = t.ns;
    float a0 = 0.f, a1 = 0.f, b0 = 0.f, b1 = 0.f;
    float c0 = 0.f, c1 = 0.f, d0 = 0.f, d1 = 0.f;
    int e = e0;
    for (; e + 4 <= e1; e += 4) {
        int s0 = esrc[e], s1 = esrc[e + 1], s2 = esrc[e + 2], s3 = esrc[e + 3];
        float w0 = ns[s0], w1 = ns[s1], w2 = ns[s2], w3 = ns[s3];
        float2 v0 = *reinterpret_cast<const float2*>(xin + (size_t)s0 * 128 + lane * 2);
        float2 v1 = *reinterpret_cast<const float2*>(xin + (size_t)s1 * 128 + lane * 2);
        float2 v2 = *reinterpret_cast<const float2*>(xin + (size_t)s2 * 128 + lane * 2);
        float2 v3 = *reinterpret_cast<const float2*>(xin + (size_t)s3 * 128 + lane * 2);
        if (RELU) {
            v0.x = fmaxf(v0.x, 0.f); v0.y = fmaxf(v0.y, 0.f);
            v1.x = fmaxf(v1.x, 0.f); v1.y = fmaxf(v1.y, 0.f);
            v2.x = fmaxf(v2.x, 0.f); v2.y = fmaxf(v2.y, 0.f);
            v3.x = fmaxf(v3.x, 0.f); v3.y = fmaxf(v3.y, 0.f);
        }
        a0 = fmaf(w0, v0.x, a0); a1 = fmaf(w0, v0.y, a1);
        b0 = fmaf(w1, v1.x, b0); b1 = fmaf(w1, v1.y, b1);
        c0 = fmaf(w2, v2.x, c0); c1 = fmaf(w2, v2.y, c1);
        d0 = fmaf(w3, v3.x, d0); d1 = fmaf(w3, v3.y, d1);
    }
    for (; e < e1; ++e) {
        int s = esrc[e];
        float w = ns[s];
        float2 v = *reinterpret_cast<const float2*>(xin + (size_t)s * 128 + lane * 2);
        if (RELU) { v.x = fmaxf(v.x, 0.f); v.y = fmaxf(v.y, 0.f); }
        a0 = fmaf(w, v.x, a0); a1 = fmaf(w, v.y, a1);
    }
    float nr = t.nd[wave];
    float r0 = ((a0 + b0) + (c0 + d0)) * nr;
    float r1 = ((a1 + b1) + (c1 + d1)) * nr;
    // split-bf16: hi = rn(v), lo = rn(v - hi)
    unsigned u0 = __float_as_uint(r0);
    unsigned h0b = (u0 + 0x7fffu + ((u0 >> 16) & 1u)) & 0xffff0000u;
    unsigned ul0 = __float_as_uint(r0 - __uint_as_float(h0b));
    unsigned u1 = __float_as_uint(r1);
    unsigned h1b = (u1 + 0x7fffu + ((u1 >> 16) & 1u)) & 0xffff0000u;
    unsigned ul1 = __float_as_uint(r1 - __uint_as_float(h1b));
    ushort2 hv, lv;
    hv.x = (unsigned short)(h0b >> 16);
    hv.y = (unsigned short)(h1b >> 16);
    lv.x = (unsigned short)((ul0 + 0x7fffu + ((ul0 >> 16) & 1u)) >> 16);
    lv.y = (unsigned short)((ul1 + 0x7fffu + ((ul1 >> 16) & 1u)) >> 16);
    *reinterpret_cast<ushort2*>(t.Ah + (size_t)wave * 128 + lane * 2) = hv;
    *reinterpret_cast<ushort2*>(t.Al + (size_t)wave * 128 + lane * 2) = lv;
}

// ---------------- MFMA GEMM: H (=|+=) sum_s A_s @ W_s + bias ----------------
// A planes: [NS][NN][128] bf16 (hi,lo). W planes: chunk-major [4][128][32].
// Block 256 thr = 4 waves; block tile 64 rows x 128 cols; wave = 32-col slice,
// 4 row-tiles x 2 col-tiles of 16x16. 3-pass split product per k-chunk.
template <int NS, int STORE>
__global__ __launch_bounds__(256) void k_gemm_mfma(
    const unsigned short* __restrict__ Ah, const unsigned short* __restrict__ Al,
    const unsigned short* __restrict__ wha, const unsigned short* __restrict__ wla,
    const unsigned short* __restrict__ whb, const unsigned short* __restrict__ wlb,
    const float* __restrict__ ba, const float* __restrict__ bb,
    float* __restrict__ H) {
    int tid = threadIdx.x;
    int w = tid >> 6, lane = tid & 63;
    int row0 = blockIdx.x * 64;
    int colbase = w * 32;
    int r16 = lane & 15;
    int koff = (lane >> 4) * 8;   // k element offset within 32-chunk

    f32x4 acc[4][2];
#pragma unroll
    for (int rt = 0; rt < 4; ++rt)
#pragma unroll
        for (int nt = 0; nt < 2; ++nt)
            acc[rt][nt] = f32x4{0.f, 0.f, 0.f, 0.f};

#pragma unroll
    for (int s = 0; s < NS; ++s) {
        const unsigned short* A_h = Ah + (size_t)s * NN * 128;
        const unsigned short* A_l = Al + (size_t)s * NN * 128;
        const unsigned short* w_h = (s == 0) ? wha : whb;
        const unsigned short* w_l = (s == 0) ? wla : wlb;
#pragma unroll
        for (int c = 0; c < 4; ++c) {
            int kbase = c * 32 + koff;
            bf16x8 ah[4], al[4], bh[2], bl[2];
#pragma unroll
            for (int rt = 0; rt < 4; ++rt) {
                int rr = rt * 16 + r16;
                // OOB rows: clamp to row 0 (results discarded by epilogue guard)
                int rc = (row0 + rr < NN) ? rr : 0;
                const unsigned short* ap = A_h + ((size_t)(row0 + rc)) * 128 + kbase;
                ah[rt] = *reinterpret_cast<const bf16x8*>(ap);
                al[rt] = *reinterpret_cast<const bf16x8*>(
                    A_l + ((size_t)(row0 + rc)) * 128 + kbase);
            }
#pragma unroll
            for (int nt = 0; nt < 2; ++nt) {
                int col = colbase + nt * 16 + r16;
                size_t widx = ((size_t)c * 128 + col) * 32 + koff;
                bh[nt] = *reinterpret_cast<const bf16x8*>(w_h + widx);
                bl[nt] = *reinterpret_cast<const bf16x8*>(w_l + widx);
            }
#pragma unroll
            for (int rt = 0; rt < 4; ++rt)
#pragma unroll
                for (int nt = 0; nt < 2; ++nt) {
                    acc[rt][nt] = MFMA16(ah[rt], bh[nt], acc[rt][nt]);
                    acc[rt][nt] = MFMA16(ah[rt], bl[nt], acc[rt][nt]);
                    acc[rt][nt] = MFMA16(al[rt], bh[nt], acc[rt][nt]);
                }
        }
    }

    // epilogue: D row = (lane>>4)*4 + j, col = lane&15 (per 16x16 tile)
    int orow = (lane >> 4) * 4;
#pragma unroll
    for (int nt = 0; nt < 2; ++nt) {
        int col = colbase + nt * 16 + r16;
        float bias = ba[col];
        if (NS == 2) bias += bb[col];
#pragma unroll
        for (int rt = 0; rt < 4; ++rt) {
#pragma unroll
            for (int j = 0; j < 4; ++j) {
                int grow = row0 + rt * 16 + orow + j;
                if (grow < NN) {
                    float* hp = H + (size_t)grow * 128 + col;
                    float v = acc[rt][nt][j] + bias;
                    if (!STORE) v += *hp;
                    *hp = v;
                }
            }
        }
    }
}

// ---------------- classifier: out = relu(H) @ Wc + bc -----------------------
__global__ __launch_bounds__(256) void k_classifier(const float* __restrict__ H,
                                                    const float* __restrict__ Wc,
                                                    const float* __restrict__ bc,
                                                    float* __restrict__ out) {
    __shared__ float sW[128 * 16];
    __shared__ float sb[16];
    int tid = threadIdx.x;
#pragma unroll
    for (int i = tid; i < 2048; i += 256) sW[i] = Wc[i];
    if (tid < 16) sb[tid] = bc[tid];
    __syncthreads();
    int node = blockIdx.x * 64 + (tid >> 2);
    if (node >= 3 * NN) return;
    int cg = (tid & 3) << 2;
    const float* h = H + (size_t)node * 128;
    float acc0 = 0.f, acc1 = 0.f, acc2 = 0.f, acc3 = 0.f;
#pragma unroll 4
    for (int k0 = 0; k0 < 128; k0 += 4) {
        float4 a4 = *reinterpret_cast<const float4*>(h + k0);
        float a;
        a = fmaxf(a4.x, 0.f);
        { float4 wv = *reinterpret_cast<const float4*>(&sW[(k0 + 0) * 16 + cg]);
          acc0 = fmaf(a, wv.x, acc0); acc1 = fmaf(a, wv.y, acc1);
          acc2 = fmaf(a, wv.z, acc2); acc3 = fmaf(a, wv.w, acc3); }
        a = fmaxf(a4.y, 0.f);
        { float4 wv = *reinterpret_cast<const float4*>(&sW[(k0 + 1) * 16 + cg]);
          acc0 = fmaf(a, wv.x, acc0); acc1 = fmaf(a, wv.y, acc1);
          acc2 = fmaf(a, wv.z, acc2); acc3 = fmaf(a, wv.w, acc3); }
        a = fmaxf(a4.z, 0.f);
        { float4 wv = *reinterpret_cast<const float4*>(&sW[(k0 + 2) * 16 + cg]);
          acc0 = fmaf(a, wv.x, acc0); acc1 = fmaf(a, wv.y, acc1);
          acc2 = fmaf(a, wv.z, acc2); acc3 = fmaf(a, wv.w, acc3); }
        a = fmaxf(a4.w, 0.f);
        { float4 wv = *reinterpret_cast<const float4*>(&sW[(k0 + 3) * 16 + cg]);
          acc0 = fmaf(a, wv.x, acc0); acc1 = fmaf(a, wv.y, acc1);
          acc2 = fmaf(a, wv.z, acc2); acc3 = fmaf(a, wv.w, acc3); }
    }
    float4 o = make_float4(acc0 + sb[cg], acc1 + sb[cg + 1],
                           acc2 + sb[cg + 2], acc3 + sb[cg + 3]);
    *reinterpret_cast<float4*>(out + (size_t)node * 16 + cg) = o;
}

// ---------------------------------------------------------------------------
extern "C" void kernel_launch(void* const* d_in, const int* in_sizes, int n_in,
                              void* d_out, int out_size, void* d_ws, size_t ws_size,
                              hipStream_t stream) {
    const float* x0 = (const float*)d_in[0];
    const float* x1 = (const float*)d_in[1];
    const float* x2 = (const float*)d_in[2];
    const float* W1 = (const float*)d_in[3];
    const float* b1 = (const float*)d_in[4];
    const float* W2 = (const float*)d_in[5];
    const float* b2 = (const float*)d_in[6];
    const float* Wc = (const float*)d_in[7];
    const float* bc = (const float*)d_in[8];
    const int* edges = (const int*)d_in[9];
    const float* x[3] = {x0, x1, x2};

    const int REL_S[9] = {0, 1, 1, 0, 2, 2, 0, 2, 1};

    // ---- workspace carve-up with overlays (~226 MB peak) ----
    char* p = (char*)d_ws;
    auto alloc = [&](size_t bytes) -> void* {
        void* r = (void*)p;
        p += (bytes + 255) & ~(size_t)255;
        return r;
    };
    float* h2 = (float*)alloc((size_t)3 * NN * 128 * sizeof(float));  // 76.8 MB
    unsigned* hist = (unsigned*)h2;    // alias: hist dead after k_sums
    float* h1 = (float*)alloc((size_t)3 * NN * 128 * sizeof(float));  // 76.8 MB
    int* cur = (int*)h1;               // alias: cur dead after k_fill
    int* deg_d = (int*)(h1 + 9 * NN);  // alias: deg_d dead after k_offsets
    unsigned short* Ah = (unsigned short*)alloc((size_t)2 * NN * 128 * 2);  // 25.6 MB
    unsigned short* Al = (unsigned short*)alloc((size_t)2 * NN * 128 * 2);  // 25.6 MB
    int* off = (int*)alloc((size_t)9 * (NN + 1) * sizeof(int));
    float* ns = (float*)alloc((size_t)9 * NN * sizeof(float));
    float* nd = (float*)alloc((size_t)9 * NN * sizeof(float));
    int* esrc = (int*)alloc((size_t)9 * EE * sizeof(int));            // 14.4 MB
    unsigned short* whi = (unsigned short*)alloc((size_t)2 * 9 * 128 * 128 * 2);
    unsigned short* wlo = (unsigned short*)alloc((size_t)2 * 9 * 128 * 128 * 2);
    unsigned short* Ah1 = Ah + (size_t)NN * 128;
    unsigned short* Al1 = Al + (size_t)NN * 128;

    // ---- CSR build + W prep (reused by both layers) ----
    k_hist<<<288, 256, 0, stream>>>(edges, hist);
    k_sums<<<(9 * (NN / 2) + 255) / 256, 256, 0, stream>>>(hist, ns, nd, deg_d);
    k_offsets<<<9, 256, 0, stream>>>(deg_d, off, cur);
    k_fill<<<(9 * EE + 255) / 256, 256, 0, stream>>>(edges, cur, esrc);
    k_wprep<<<(2 * 9 * 128 * 128 + 255) / 256, 256, 0, stream>>>(W1, W2, whi, wlo);

    const dim3 agg2_grid(12500, 2);
    const dim3 agg1_grid(12500, 1);
    const int gemm_blocks = (NN + 63) / 64;   // 782

    auto mk = [&](int r, const float* xin, unsigned short* ah, unsigned short* al) -> AggT {
        return AggT{xin, off + r * (NN + 1), esrc + (size_t)r * EE,
                    ns + r * NN, nd + r * NN, ah, al};
    };
    auto wp = [&](int layer, int r) { return (size_t)(layer * 9 + r) * 16384; };

    // ======== layer 1 (inputs x[], no relu) ========
    {
        const float* b = b1; float* h = h1; const int L = 0;
        k_agg2<0><<<agg2_grid, 256, 0, stream>>>(mk(2, x[REL_S[2]], Ah, Al),
                                                 mk(3, x[REL_S[3]], Ah1, Al1));
        k_gemm_mfma<2, 1><<<gemm_blocks, 256, 0, stream>>>(
            Ah, Al, whi + wp(L, 2), wlo + wp(L, 2), whi + wp(L, 3), wlo + wp(L, 3),
            b + 2 * 128, b + 3 * 128, h + (size_t)0 * NN * 128);
        k_agg2<0><<<agg2_grid, 256, 0, stream>>>(mk(5, x[REL_S[5]], Ah, Al),
                                                 mk(6, x[REL_S[6]], Ah1, Al1));
        k_gemm_mfma<2, 0><<<gemm_blocks, 256, 0, stream>>>(
            Ah, Al, whi + wp(L, 5), wlo + wp(L, 5), whi + wp(L, 6), wlo + wp(L, 6),
            b + 5 * 128, b + 6 * 128, h + (size_t)0 * NN * 128);
        k_agg2<0><<<agg2_grid, 256, 0, stream>>>(mk(4, x[REL_S[4]], Ah, Al),
                                                 mk(8, x[REL_S[8]], Ah1, Al1));
        k_gemm_mfma<2, 1><<<gemm_blocks, 256, 0, stream>>>(
            Ah, Al, whi + wp(L, 4), wlo + wp(L, 4), whi + wp(L, 8), wlo + wp(L, 8),
            b + 4 * 128, b + 8 * 128, h + (size_t)1 * NN * 128);
        k_agg2<0><<<agg2_grid, 256, 0, stream>>>(mk(0, x[REL_S[0]], Ah, Al),
                                                 mk(1, x[REL_S[1]], Ah1, Al1));
        k_gemm_mfma<2, 1><<<gemm_blocks, 256, 0, stream>>>(
            Ah, Al, whi + wp(L, 0), wlo + wp(L, 0), whi + wp(L, 1), wlo + wp(L, 1),
            b + 0 * 128, b + 1 * 128, h + (size_t)2 * NN * 128);
        k_agg2<0><<<agg1_grid, 256, 0, stream>>>(mk(7, x[REL_S[7]], Ah, Al),
                                                 mk(7, x[REL_S[7]], Ah, Al));
        k_gemm_mfma<1, 0><<<gemm_blocks, 256, 0, stream>>>(
            Ah, Al, whi + wp(L, 7), wlo + wp(L, 7), whi + wp(L, 7), wlo + wp(L, 7),
            b + 7 * 128, b + 7 * 128, h + (size_t)2 * NN * 128);
    }

    // ======== layer 2 (inputs relu(h1), folded into gather) ========
    {
        const float* b = b2; float* h = h2; const int L = 1;
        auto hin = [&](int r) { return h1 + (size_t)REL_S[r] * NN * 128; };
        k_agg2<1><<<agg2_grid, 256, 0, stream>>>(mk(2, hin(2), Ah, Al),
                                                 mk(3, hin(3), Ah1, Al1));
        k_gemm_mfma<2, 1><<<gemm_blocks, 256, 0, stream>>>(
            Ah, Al, whi + wp(L, 2), wlo + wp(L, 2), whi + wp(L, 3), wlo + wp(L, 3),
            b + 2 * 128, b + 3 * 128, h + (size_t)0 * NN * 128);
        k_agg2<1><<<agg2_grid, 256, 0, stream>>>(mk(5, hin(5), Ah, Al),
                                                 mk(6, hin(6), Ah1, Al1));
        k_gemm_mfma<2, 0><<<gemm_blocks, 256, 0, stream>>>(
            Ah, Al, whi + wp(L, 5), wlo + wp(L, 5), whi + wp(L, 6), wlo + wp(L, 6),
            b + 5 * 128, b + 6 * 128, h + (size_t)0 * NN * 128);
        k_agg2<1><<<agg2_grid, 256, 0, stream>>>(mk(4, hin(4), Ah, Al),
                                                 mk(8, hin(8), Ah1, Al1));
        k_gemm_mfma<2, 1><<<gemm_blocks, 256, 0, stream>>>(
            Ah, Al, whi + wp(L, 4), wlo + wp(L, 4), whi + wp(L, 8), wlo + wp(L, 8),
            b + 4 * 128, b + 8 * 128, h + (size_t)1 * NN * 128);
        k_agg2<1><<<agg2_grid, 256, 0, stream>>>(mk(0, hin(0), Ah, Al),
                                                 mk(1, hin(1), Ah1, Al1));
        k_gemm_mfma<2, 1><<<gemm_blocks, 256, 0, stream>>>(
            Ah, Al, whi + wp(L, 0), wlo + wp(L, 0), whi + wp(L, 1), wlo + wp(L, 1),
            b + 0 * 128, b + 1 * 128, h + (size_t)2 * NN * 128);
        k_agg2<1><<<agg1_grid, 256, 0, stream>>>(mk(7, hin(7), Ah, Al),
                                                 mk(7, hin(7), Ah, Al));
        k_gemm_mfma<1, 0><<<gemm_blocks, 256, 0, stream>>>(
            Ah, Al, whi + wp(L, 7), wlo + wp(L, 7), whi + wp(L, 7), wlo + wp(L, 7),
            b + 7 * 128, b + 7 * 128, h + (size_t)2 * NN * 128);
    }

    // ---- classifier: out = relu(h2) @ Wc + bc ----
    k_classifier<<<(3 * NN + 63) / 64, 256, 0, stream>>>(h2, Wc, bc, (float*)d_out);
}